// Round 1
// baseline (501.352 us; speedup 1.0000x reference)
//
#include <hip/hip_runtime.h>

#define BB 32
#define TT 512
#define KK 48
#define KK2 (KK*KK)   // 2304
#define START_TAG 46
#define STOP_TAG 47
#define L2E 1.4426950408889634f
#define LN2 0.6931471805599453f

__device__ inline float fast_exp2(float x) {
#if __has_builtin(__builtin_amdgcn_exp2f)
  return __builtin_amdgcn_exp2f(x);
#else
  return exp2f(x);
#endif
}
__device__ inline float fast_log2(float x) {
#if __has_builtin(__builtin_amdgcn_logf)
  return __builtin_amdgcn_logf(x);
#else
  return log2f(x);
#endif
}

// ---------------- gold score: sum_b sum_{t<len[b]} feat[b,t].flat[target[b,t]] ----------------
__global__ __launch_bounds__(256) void gold_kernel(const float* __restrict__ feat,
                                                   const int* __restrict__ targets,
                                                   const int* __restrict__ lengths,
                                                   float* __restrict__ ws) {
  int b = blockIdx.x;
  int len = lengths[b];
  float sum = 0.f;
  for (int t = threadIdx.x; t < TT; t += 256) {
    if (t < len) {
      int tgt = targets[b * TT + t];
      sum += feat[(size_t)(b * TT + t) * KK2 + tgt];
    }
  }
  #pragma unroll
  for (int m = 1; m < 64; m <<= 1) sum += __shfl_xor(sum, m, 64);
  __shared__ float part[4];
  if ((threadIdx.x & 63) == 0) part[threadIdx.x >> 6] = sum;
  __syncthreads();
  if (threadIdx.x == 0) ws[b] = part[0] + part[1] + part[2] + part[3];
}

// ---------------- forward scan: one block per batch ----------------
// 192 threads = 3 waves. thread -> (j = tid>>2 in [0,48), ig = tid&3 in [0,4))
// thread reduces i in [ig*12, ig*12+12) for column j; 4-lane shfl combine.
// carry kept in LDS in log2-domain (pre-multiplied by log2(e)), double-buffered.
// features prefetched 4 steps ahead into a register ring xb[4][12].
__global__ __launch_bounds__(192, 1) void scan_kernel(const float* __restrict__ feat,
                                                      const int* __restrict__ lengths,
                                                      float* __restrict__ ws) {
  int b = blockIdx.x;
  int len = lengths[b];
  int tid = threadIdx.x;
  int j = tid >> 2;   // 0..47
  int ig = tid & 3;   // 0..3

  __shared__ float carry[2][KK];

  const float* fb = feat + (size_t)b * TT * KK2;

  // init: carry_l2e[j] = feat[b,0,START,j] * log2(e)
  if (tid < KK) carry[0][tid] = fb[START_TAG * KK + tid] * L2E;
  __syncthreads();

  // register prefetch ring: xb[u] holds raw feature values for a future step
  float xb[4][12];
  #pragma unroll
  for (int u = 0; u < 4; ++u) {
    int t = 1 + u;  // always valid (TT=512)
    const float* p = fb + (size_t)t * KK2 + ig * 12 * KK + j;
    #pragma unroll
    for (int r = 0; r < 12; ++r) xb[u][r] = p[r * KK];
  }

  for (int tb = 1; tb < len; tb += 4) {
    #pragma unroll
    for (int u = 0; u < 4; ++u) {
      int t = tb + u;
      if (t < len) {                    // block-uniform guard
        int rd = (t - 1) & 1, wr = t & 1;
        // carry slice for i = ig*12 .. ig*12+11  (3x ds_read_b128, broadcast, conflict-free)
        float c[12];
        #pragma unroll
        for (int q = 0; q < 3; ++q) {
          float4 cv = *reinterpret_cast<const float4*>(&carry[rd][ig * 12 + q * 4]);
          c[q * 4 + 0] = cv.x; c[q * 4 + 1] = cv.y; c[q * 4 + 2] = cv.z; c[q * 4 + 3] = cv.w;
        }
        // pass 1: x = feat*log2e + carry_l2e; running max (balanced tree)
        float x[12];
        #pragma unroll
        for (int r = 0; r < 12; ++r) x[r] = fmaf(xb[u][r], L2E, c[r]);
        float m0 = fmaxf(fmaxf(x[0], x[1]), fmaxf(x[2], x[3]));
        float m1 = fmaxf(fmaxf(x[4], x[5]), fmaxf(x[6], x[7]));
        float m2 = fmaxf(fmaxf(x[8], x[9]), fmaxf(x[10], x[11]));
        float m = fmaxf(fmaxf(m0, m1), m2);
        m = fmaxf(m, __shfl_xor(m, 1));
        m = fmaxf(m, __shfl_xor(m, 2));
        // pass 2: sum of 2^(x-m), 4 accumulators to break the add chain
        float s0 = 0.f, s1 = 0.f, s2 = 0.f, s3 = 0.f;
        #pragma unroll
        for (int r = 0; r < 12; r += 4) {
          s0 += fast_exp2(x[r + 0] - m);
          s1 += fast_exp2(x[r + 1] - m);
          s2 += fast_exp2(x[r + 2] - m);
          s3 += fast_exp2(x[r + 3] - m);
        }
        float s = (s0 + s1) + (s2 + s3);
        s += __shfl_xor(s, 1);
        s += __shfl_xor(s, 2);
        float cn = m + fast_log2(s);   // new carry in log2 domain
        if (ig == 0) carry[wr][j] = cn;
      }
      // issue prefetch for step t+4 into the slot just consumed (always executed)
      {
        int tn = t + 4; if (tn > TT - 1) tn = TT - 1;
        const float* p = fb + (size_t)tn * KK2 + ig * 12 * KK + j;
        #pragma unroll
        for (int r = 0; r < 12; ++r) xb[u][r] = p[r * KK];
      }
      if (t < len) __syncthreads();     // block-uniform
    }
  }

  if (tid == 0) {
    int rd = (len - 1) & 1;
    ws[BB + b] = carry[rd][STOP_TAG] * LN2;   // back to natural-log domain
  }
}

// ---------------- finalize: ( sum_b final_stop[b] - sum_b gold[b] ) / B ----------------
__global__ void finalize_kernel(const float* __restrict__ ws, float* __restrict__ out) {
  int l = threadIdx.x;
  float d = 0.f;
  if (l < BB) d = ws[BB + l] - ws[l];
  #pragma unroll
  for (int m = 1; m < 64; m <<= 1) d += __shfl_xor(d, m, 64);
  if (l == 0) out[0] = d / (float)BB;
}

extern "C" void kernel_launch(void* const* d_in, const int* in_sizes, int n_in,
                              void* d_out, int out_size, void* d_ws, size_t ws_size,
                              hipStream_t stream) {
  const float* feat   = (const float*)d_in[0];
  const int* targets  = (const int*)d_in[1];
  const int* lengths  = (const int*)d_in[2];
  float* ws  = (float*)d_ws;
  float* out = (float*)d_out;

  gold_kernel<<<BB, 256, 0, stream>>>(feat, targets, lengths, ws);
  scan_kernel<<<BB, 192, 0, stream>>>(feat, lengths, ws);
  finalize_kernel<<<1, 64, 0, stream>>>(ws, out);
}